// Round 2
// baseline (28873.831 us; speedup 1.0000x reference)
//
#include <hip/hip_runtime.h>
#include <math.h>

#define EMBD 512
#define HIDD 1024
#define NVOC 32000
#define SEQL 64
#define NVT  500

// ---- ws layout (float offsets) ----
// h0 0 | h1 65536 | x 131072 | gi0 163840 | gi1 360448 | gh0 557056 | gh1 753664
// pm 950272 | ps 982272 | bv 1014272 | bl 1046272 | bi(int) 1078272 | end 1110272 (~4.4MB)

__global__ __launch_bounds__(256) void k_init(const float* __restrict__ emb,
                                              float* __restrict__ ws) {
    int b = blockIdx.x, tid = threadIdx.x;
    float* h0 = ws;
    float* x  = ws + 131072;
    for (int j = tid; j < HIDD; j += 256) h0[b * HIDD + j] = 0.f;
    for (int k = tid; k < EMBD; k += 256) x[b * EMBD + k] = emb[k];
}

// gates: grid (48, 2 kchunk, 2 mat). Block = 64 rows, 4 waves x 16 rows.
// out[(n)*64+b] partial over K/2; bias added in kc==0.
__global__ __launch_bounds__(256) void k_gates(
    const float* __restrict__ w_ih, const float* __restrict__ b_ih,
    const float* __restrict__ xin,
    const float* __restrict__ w_hh, const float* __restrict__ b_hh,
    const float* __restrict__ h,
    float* __restrict__ gi0, float* __restrict__ gi1,
    float* __restrict__ gh0, float* __restrict__ gh1) {
    __shared__ float Xs[32][64];
    int tid = threadIdx.x;
    int wid = __builtin_amdgcn_readfirstlane(tid >> 6);
    int lane = tid & 63;
    int mat = blockIdx.z, kc = blockIdx.y;
    const float* W    = mat ? w_hh : w_ih;
    const float* X    = mat ? h    : xin;
    const float* bias = mat ? b_hh : b_ih;
    float* out = mat ? (kc ? gh1 : gh0) : (kc ? gi1 : gi0);
    int K  = mat ? HIDD : EMBD;
    int Kh = K >> 1;
    int kbase = kc * Kh;
    int rbase = blockIdx.x * 64 + wid * 16;

    float acc[16];
#pragma unroll
    for (int v = 0; v < 16; ++v) acc[v] = 0.f;

    for (int k0 = 0; k0 < Kh; k0 += 32) {
        int r = tid >> 2, c = (tid & 3) * 8;
        const float* hp = X + (size_t)r * K + kbase + k0 + c;
        float4 a0 = *(const float4*)hp;
        float4 a1 = *(const float4*)(hp + 4);
        __syncthreads();
        Xs[c + 0][r] = a0.x; Xs[c + 1][r] = a0.y; Xs[c + 2][r] = a0.z; Xs[c + 3][r] = a0.w;
        Xs[c + 4][r] = a1.x; Xs[c + 5][r] = a1.y; Xs[c + 6][r] = a1.z; Xs[c + 7][r] = a1.w;
        __syncthreads();
        const float* wb = W + (size_t)rbase * K + kbase + k0;
#pragma unroll
        for (int kk = 0; kk < 32; ++kk) {
            float xk = Xs[kk][lane];
#pragma unroll
            for (int v = 0; v < 16; ++v)
                acc[v] += wb[(size_t)v * K + kk] * xk;
        }
    }
#pragma unroll
    for (int v = 0; v < 16; ++v) {
        float o = acc[v] + (kc == 0 ? bias[rbase + v] : 0.f);
        out[(rbase + v) * 64 + lane] = o;
    }
}

__global__ __launch_bounds__(256) void k_gru(
    const float* __restrict__ gi0, const float* __restrict__ gi1,
    const float* __restrict__ gh0, const float* __restrict__ gh1,
    const float* __restrict__ h_in, float* __restrict__ h_out) {
    int tid = blockIdx.x * 256 + threadIdx.x;
    int b = tid & 63, j = tid >> 6;
    int i0 = j * 64 + b, i1 = (j + 1024) * 64 + b, i2 = (j + 2048) * 64 + b;
    float ir = gi0[i0] + gi1[i0], iz = gi0[i1] + gi1[i1], in_ = gi0[i2] + gi1[i2];
    float hr = gh0[i0] + gh1[i0], hz = gh0[i1] + gh1[i1], hn = gh0[i2] + gh1[i2];
    float h = h_in[b * HIDD + j];
    float r = 1.f / (1.f + expf(-(ir + hr)));
    float z = 1.f / (1.f + expf(-(iz + hz)));
    float n = tanhf(in_ + r * hn);
    h_out[b * HIDD + j] = (1.f - z) * n + z * h;
}

// logits + fused per-block softmax/gumbel partials. grid 500, block 256 (4 waves x 16 rows).
// lane = batch. Never materializes logits.
__global__ __launch_bounds__(256) void k_logits(
    const float* __restrict__ w_out, const float* __restrict__ b_out,
    const float* __restrict__ h, const float* __restrict__ gum,
    const float* __restrict__ eps,
    float* __restrict__ pm, float* __restrict__ ps,
    float* __restrict__ bv, float* __restrict__ bl, int* __restrict__ bi, int t) {
    __shared__ float Xs[32][64];
    __shared__ float rm[4][64], rs[4][64], rv[4][64], rl[4][64];
    __shared__ int   ri[4][64];
    int tid = threadIdx.x;
    int wid = __builtin_amdgcn_readfirstlane(tid >> 6);
    int lane = tid & 63;
    int v0 = blockIdx.x * 64;
    int rbase = v0 + wid * 16;

    float acc[16];
#pragma unroll
    for (int v = 0; v < 16; ++v) acc[v] = 0.f;

    for (int k0 = 0; k0 < HIDD; k0 += 32) {
        int r = tid >> 2, c = (tid & 3) * 8;
        const float* hp = h + (size_t)r * HIDD + k0 + c;
        float4 a0 = *(const float4*)hp;
        float4 a1 = *(const float4*)(hp + 4);
        __syncthreads();
        Xs[c + 0][r] = a0.x; Xs[c + 1][r] = a0.y; Xs[c + 2][r] = a0.z; Xs[c + 3][r] = a0.w;
        Xs[c + 4][r] = a1.x; Xs[c + 5][r] = a1.y; Xs[c + 6][r] = a1.z; Xs[c + 7][r] = a1.w;
        __syncthreads();
        const float* wb = w_out + (size_t)rbase * HIDD + k0;
#pragma unroll
        for (int kk = 0; kk < 32; ++kk) {
            float xk = Xs[kk][lane];
#pragma unroll
            for (int v = 0; v < 16; ++v)
                acc[v] += wb[(size_t)v * HIDD + kk] * xk;
        }
    }

    // per-lane epilogue: 16 logits for batch=lane, rows rbase..rbase+15
    float lv[16];
#pragma unroll
    for (int v = 0; v < 16; ++v) lv[v] = acc[v] + b_out[rbase + v];
    float m = lv[0];
#pragma unroll
    for (int v = 1; v < 16; ++v) m = fmaxf(m, lv[v]);
    float s = 0.f;
#pragma unroll
    for (int v = 0; v < 16; ++v) s += expf(lv[v] - m);

    bool draw = eps[t * 64 + lane] <= 0.5f;
    const float LOGV = logf(32000.0f);
    const float* grow = gum + ((size_t)t * 64 + lane) * NVOC + rbase;
    float bestv = -INFINITY, bestl = 0.f; int besti = 0x7fffffff;
#pragma unroll
    for (int v = 0; v < 16; ++v) {
        float u = grow[v];
        u = fminf(fmaxf(u, 1e-12f), 1.0f);
        float g = -logf(-logf(u));
        float sc = (draw ? -LOGV : lv[v]) + g;
        if (sc > bestv) { bestv = sc; besti = rbase + v; bestl = lv[v]; }
    }

    rm[wid][lane] = m; rs[wid][lane] = s; rv[wid][lane] = bestv;
    rl[wid][lane] = bestl; ri[wid][lane] = besti;
    __syncthreads();
    if (tid < 64) {
        int b = tid;
        float M = rm[0][b];
#pragma unroll
        for (int w = 1; w < 4; ++w) M = fmaxf(M, rm[w][b]);
        float S = 0.f;
#pragma unroll
        for (int w = 0; w < 4; ++w) S += rs[w][b] * expf(rm[w][b] - M);
        float BV = rv[0][b], BL = rl[0][b]; int BI = ri[0][b];
#pragma unroll
        for (int w = 1; w < 4; ++w) {
            float ov = rv[w][b]; int oi = ri[w][b];
            if (ov > BV || (ov == BV && oi < BI)) { BV = ov; BI = oi; BL = rl[w][b]; }
        }
        int o = blockIdx.x * 64 + b;
        pm[o] = M; ps[o] = S; bv[o] = BV; bl[o] = BL; bi[o] = BI;
    }
}

// final: reduce 500 partials per batch row, outputs, emb gather. grid 64.
__global__ __launch_bounds__(256) void k_final(
    const float* __restrict__ pm, const float* __restrict__ ps,
    const float* __restrict__ bv, const float* __restrict__ bl,
    const int* __restrict__ bi, const float* __restrict__ eps,
    const float* __restrict__ emb,
    float* __restrict__ xout, float* __restrict__ out, int t) {
    int b = blockIdx.x, tid = threadIdx.x;
    __shared__ float sr[256], sv[256], sl[256];
    __shared__ int   si[256];
    __shared__ int   s_samp;

    float M = -INFINITY;
    for (int c = tid; c < NVT; c += 256) M = fmaxf(M, pm[c * 64 + b]);
    sr[tid] = M;
    __syncthreads();
    for (int st = 128; st > 0; st >>= 1) {
        if (tid < st) sr[tid] = fmaxf(sr[tid], sr[tid + st]);
        __syncthreads();
    }
    M = sr[0];
    __syncthreads();
    float S = 0.f;
    for (int c = tid; c < NVT; c += 256) S += ps[c * 64 + b] * expf(pm[c * 64 + b] - M);
    sr[tid] = S;
    __syncthreads();
    for (int st = 128; st > 0; st >>= 1) {
        if (tid < st) sr[tid] += sr[tid + st];
        __syncthreads();
    }
    float lse = M + logf(sr[0]);
    __syncthreads();

    float BV = -INFINITY, BL = 0.f; int BI = 0x7fffffff;
    for (int c = tid; c < NVT; c += 256) {
        float ov = bv[c * 64 + b]; int oi = bi[c * 64 + b];
        if (ov > BV || (ov == BV && oi < BI)) { BV = ov; BI = oi; BL = bl[c * 64 + b]; }
    }
    sv[tid] = BV; si[tid] = BI; sl[tid] = BL;
    __syncthreads();
    for (int st = 128; st > 0; st >>= 1) {
        if (tid < st) {
            float ov = sv[tid + st]; int oi = si[tid + st];
            if (ov > sv[tid] || (ov == sv[tid] && oi < si[tid])) {
                sv[tid] = ov; si[tid] = oi; sl[tid] = sl[tid + st];
            }
        }
        __syncthreads();
    }
    if (tid == 0) {
        int sampled = si[0];
        s_samp = sampled;
        float lp = sl[0] - lse;
        bool draw = eps[t * 64 + b] <= 0.5f;
        const float LOGV = logf(32000.0f);
        float bs = draw ? -LOGV : lp;
        float off = fminf(fmaxf(expf(bs), 0.001f), 1.0f);
        float corr = expf(lp) / off;
        out[b * SEQL + t] = (float)sampled;
        out[4096 + b * SEQL + t] = corr;
        out[8192 + b * SEQL + t] = lp;
    }
    __syncthreads();
    const float* erow = emb + (size_t)s_samp * EMBD;
    for (int k = tid; k < EMBD; k += 256) xout[b * EMBD + k] = erow[k];
}

extern "C" void kernel_launch(void* const* d_in, const int* in_sizes, int n_in,
                              void* d_out, int out_size, void* d_ws, size_t ws_size,
                              hipStream_t stream) {
    const float* emb   = (const float*)d_in[0];
    const float* w_ih  = (const float*)d_in[1];
    const float* w_hh  = (const float*)d_in[2];
    const float* b_ih  = (const float*)d_in[3];
    const float* b_hh  = (const float*)d_in[4];
    const float* w_out = (const float*)d_in[5];
    const float* b_out = (const float*)d_in[6];
    const float* gum   = (const float*)d_in[7];
    const float* eps   = (const float*)d_in[8];
    float* out = (float*)d_out;
    float* ws  = (float*)d_ws;

    float* h0  = ws;
    float* h1  = ws + 65536;
    float* x   = ws + 131072;
    float* gi0 = ws + 163840;
    float* gi1 = ws + 360448;
    float* gh0 = ws + 557056;
    float* gh1 = ws + 753664;
    float* pm  = ws + 950272;
    float* psm = ws + 982272;
    float* bv  = ws + 1014272;
    float* bl  = ws + 1046272;
    int*   bi  = (int*)(ws + 1078272);

    k_init<<<64, 256, 0, stream>>>(emb, ws);
    for (int t = 0; t < SEQL; ++t) {
        float* hin  = (t & 1) ? h1 : h0;
        float* hout = (t & 1) ? h0 : h1;
        k_gates<<<dim3(48, 2, 2), 256, 0, stream>>>(w_ih, b_ih, x, w_hh, b_hh, hin,
                                                    gi0, gi1, gh0, gh1);
        k_gru<<<256, 256, 0, stream>>>(gi0, gi1, gh0, gh1, hin, hout);
        k_logits<<<NVT, 256, 0, stream>>>(w_out, b_out, hout, gum, eps,
                                          pm, psm, bv, bl, bi, t);
        k_final<<<64, 256, 0, stream>>>(pm, psm, bv, bl, bi, eps, emb, x, out, t);
    }
}